// Round 5
// baseline (3710.240 us; speedup 1.0000x reference)
//
#include <hip/hip_runtime.h>

#define NB 64   // batch
#define CS 64   // states
#define LL 8192 // sequence length

__device__ __forceinline__ float uif(unsigned int u) { return __uint_as_float(u); }
__device__ __forceinline__ unsigned int fiu(float f) { return __float_as_uint(f); }

// Compiler-visible DPP rotate: v_mov_b32_dpp row_ror:R, which GCNDPPCombine
// folds into the consuming v_fmac_f32. No inline asm -> the register
// allocator sees normal uses of E (keeps them in arch VGPRs, no AGPR-copy
// per use as with asm "v" constraints in R2-R4), and hazards are handled
// by the backend.
#define ROT(X, R)                                                               \
  uif((unsigned)__builtin_amdgcn_update_dpp((int)fiu(X), (int)fiu(X),           \
                                            0x120 + R, 0xf, 0xf, false))

#define ROW4(R)                                                                 \
  acc0 = fmaf(ROT(qr0, R), Em[0][R], acc0);                                     \
  acc1 = fmaf(ROT(qr1, R), Em[1][R], acc1);                                     \
  acc2 = fmaf(ROT(qr2, R), Em[2][R], acc2);                                     \
  acc3 = fmaf(ROT(qr3, R), Em[3][R], acc3)

__device__ __forceinline__ void crf_scan_block(const float* __restrict__ obs,
                                               const float* __restrict__ trans,
                                               float* __restrict__ out,
                                               int n, int j) {
  // one-off DPP direction calibration (wave-uniform)
  int w = __builtin_amdgcn_update_dpp(0, j, 0x121 /*row_ror:1*/, 0xf, 0xf, true);
  const int dsel = __builtin_amdgcn_readlane(w, 1);

  // E_perm[g][r] at lane j = exp(T[i][j]), i = 16g + ((j -/+ r) & 15).
  // All indices are compile-time after unroll.
  float Em[4][16];
#pragma unroll
  for (int g = 0; g < 4; ++g) {
#pragma unroll
    for (int r = 0; r < 16; ++r) {
      int irm = (j - r) & 15;
      int irp = (j + r) & 15;
      int ir = (dsel == 0) ? irm : irp;
      Em[g][r] = __expf(trans[(16 * g + ir) * CS + j]);
    }
  }

  const float* __restrict__ row = obs + ((size_t)n * CS + j) * (size_t)LL;
  float4 a0 = *(const float4*)(row);
  float4 a1 = *(const float4*)(row + 4);

  float q = __expf(a0.x);  // alpha0 = em[0]
  int carry = 0;

#pragma unroll 1
  for (int c = 0; c < LL / 8; ++c) {
    const int cn = (c + 1 < LL / 8) ? c + 1 : (LL / 8 - 1);
    float4 b0 = *(const float4*)(row + 8 * cn);
    float4 b1 = *(const float4*)(row + 8 * cn + 4);

    float e0 = __expf(a0.x), e1 = __expf(a0.y), e2 = __expf(a0.z),
          e3 = __expf(a0.w), e4 = __expf(a1.x), e5 = __expf(a1.y),
          e6 = __expf(a1.z), e7 = __expf(a1.w);

#pragma unroll
    for (int k = 0; k < 8; ++k) {
      if (c == 0 && k == 0) continue;  // t=0 consumed by init

      // replicate q row-groups to all lanes: qr_g[j] = q[16g + (j&15)]
      unsigned qb = fiu(q);
      auto h = __builtin_amdgcn_permlane16_swap(qb, qb, false, false);
      auto A = __builtin_amdgcn_permlane32_swap(h[0], h[0], false, false);
      auto B = __builtin_amdgcn_permlane32_swap(h[1], h[1], false, false);
      float qr0 = uif(A[0]), qr2 = uif(A[1]);
      float qr1 = uif(B[0]), qr3 = uif(B[1]);

      float acc0 = qr0 * Em[0][0];
      float acc1 = qr1 * Em[1][0];
      float acc2 = qr2 * Em[2][0];
      float acc3 = qr3 * Em[3][0];
      ROW4(1);  ROW4(2);  ROW4(3);  ROW4(4);  ROW4(5);
      ROW4(6);  ROW4(7);  ROW4(8);  ROW4(9);  ROW4(10);
      ROW4(11); ROW4(12); ROW4(13); ROW4(14); ROW4(15);
      float s = (acc0 + acc1) + (acc2 + acc3);
      float ee = (k == 0) ? e0 : (k == 1) ? e1 : (k == 2) ? e2 : (k == 3) ? e3
               : (k == 4) ? e4 : (k == 5) ? e5 : (k == 6) ? e6 : e7;
      q = s * ee;

      // exact power-of-two renorm every 4 steps (lane-0 exponent proxy)
      if ((k & 3) == 3) {
        int q0 = __builtin_amdgcn_readfirstlane((int)fiu(q));
        int e = ((q0 >> 23) & 0xff) - 126;
        carry += e;
        q = uif(fiu(q) - (unsigned)(e << 23));
      }
    }
    a0 = b0; a1 = b1;
  }

  // log_Z = ln2*carry + log(sum_j q[j])
  float s = q;
#pragma unroll
  for (int off = 32; off > 0; off >>= 1) s += __shfl_xor(s, off, 64);
  if (j == 0) {
    float logZ = (float)carry * 0.6931471805599453f + __logf(s);
    atomicAdd(out, logZ * (1.0f / NB));
  }
}

__device__ __forceinline__ void crf_gold_block(const float* __restrict__ obs,
                                               const float* __restrict__ trans,
                                               const int* __restrict__ tgt,
                                               float* __restrict__ out, int n) {
  const int tid = threadIdx.x;
  const int* __restrict__ trow = tgt + (size_t)n * LL;
  float acc = 0.f;
  for (int t = tid; t < LL; t += 256) {
    int s = trow[t];
    acc += obs[((size_t)n * CS + s) * (size_t)LL + t];
    if (t + 1 < LL) acc += trans[s * CS + trow[t + 1]];
  }
#pragma unroll
  for (int off = 32; off > 0; off >>= 1) acc += __shfl_xor(acc, off, 64);
  __shared__ float red[4];
  if ((tid & 63) == 0) red[tid >> 6] = acc;
  __syncthreads();
  if (tid == 0) {
    float tot = red[0] + red[1] + red[2] + red[3];
    atomicAdd(out, -tot * (1.0f / NB));
  }
}

// Fused: blocks [0,64) run the scan (threads 0-63), blocks [64,128) run the
// gold gather-reduce concurrently on other CUs.
__global__ __launch_bounds__(256, 1)
void crf_fused(const float* __restrict__ obs, const float* __restrict__ trans,
               const int* __restrict__ tgt, float* __restrict__ out) {
  const int b = blockIdx.x;
  if (b < NB) {
    if (threadIdx.x < 64)
      crf_scan_block(obs, trans, out, b, threadIdx.x);
  } else {
    crf_gold_block(obs, trans, tgt, out, b - NB);
  }
}

extern "C" void kernel_launch(void* const* d_in, const int* in_sizes, int n_in,
                              void* d_out, int out_size, void* d_ws, size_t ws_size,
                              hipStream_t stream) {
  const float* obs   = (const float*)d_in[0];
  const float* trans = (const float*)d_in[1];
  const int*   tgt   = (const int*)d_in[2];
  float* out = (float*)d_out;

  hipMemsetAsync(out, 0, sizeof(float), stream);
  crf_fused<<<2 * NB, 256, 0, stream>>>(obs, trans, tgt, out);
}

// Round 6
// 1602.119 us; speedup vs baseline: 2.3158x; 2.3158x over previous
//
#include <hip/hip_runtime.h>

#define NB 64   // batch
#define CS 64   // states
#define LL 8192 // sequence length

__device__ __forceinline__ float uif(unsigned int u) { return __uint_as_float(u); }
__device__ __forceinline__ unsigned int fiu(float f) { return __float_as_uint(f); }

// DPP-fused MAC: acc += row_ror(q) * E   (rotation on src0 comes free)
#define FMAC_DPP(ACC, Q, EV, R)                                                 \
  asm volatile("v_fmac_f32_dpp %0, %1, %2 row_ror:" #R                          \
               " row_mask:0xf bank_mask:0xf"                                    \
               : "+v"(ACC) : "v"(Q), "v"(EV))
// DPP mul (accumulator-chain start, no zero-init needed)
#define MUL_DPP(DST, Q, EV, R)                                                  \
  asm volatile("v_mul_f32_dpp %0, %1, %2 row_ror:" #R                           \
               " row_mask:0xf bank_mask:0xf"                                    \
               : "=v"(DST) : "v"(Q), "v"(EV))

// 8 MACs: even rotation RE into accA0..3, odd RO into accB0..3.
#define ROWPAIR(RE, RO)                                                         \
  FMAC_DPP(accA0, qr0, Em[0][RE], RE);                                          \
  FMAC_DPP(accA1, qr1, Em[1][RE], RE);                                          \
  FMAC_DPP(accA2, qr2, Em[2][RE], RE);                                          \
  FMAC_DPP(accA3, qr3, Em[3][RE], RE);                                          \
  FMAC_DPP(accB0, qr0, Em[0][RO], RO);                                          \
  FMAC_DPP(accB1, qr1, Em[1][RO], RO);                                          \
  FMAC_DPP(accB2, qr2, Em[2][RO], RO);                                          \
  FMAC_DPP(accB3, qr3, Em[3][RO], RO)

__device__ __forceinline__ void crf_scan_block(const float* __restrict__ obs,
                                               const float* __restrict__ trans,
                                               float* __restrict__ out,
                                               int n, int j) {
  // one-off DPP direction calibration (wave-uniform)
  int w = __builtin_amdgcn_update_dpp(0, j, 0x121 /*row_ror:1*/, 0xf, 0xf, true);
  const int dsel = __builtin_amdgcn_readlane(w, 1);

  // E_perm[g][r] at lane j = exp(T[i][j]), i = 16g + ((j -/+ r) & 15).
  // Fully unrolled -> compile-time indices; with waves_per_eu(1,1) the
  // allocator has a 512-VGPR budget and keeps all 64 in registers.
  float Em[4][16];
#pragma unroll
  for (int g = 0; g < 4; ++g) {
#pragma unroll
    for (int r = 0; r < 16; ++r) {
      int irm = (j - r) & 15;
      int irp = (j + r) & 15;
      int ir = (dsel == 0) ? irm : irp;
      Em[g][r] = __expf(trans[(16 * g + ir) * CS + j]);
    }
  }

  const float* __restrict__ row = obs + ((size_t)n * CS + j) * (size_t)LL;
  float4 a0 = *(const float4*)(row);
  float4 a1 = *(const float4*)(row + 4);

  float q = __expf(a0.x);  // alpha0 = em[0]
  int carry = 0;

#pragma unroll 1
  for (int c = 0; c < LL / 8; ++c) {
    const int cn = (c + 1 < LL / 8) ? c + 1 : (LL / 8 - 1);
    float4 b0 = *(const float4*)(row + 8 * cn);
    float4 b1 = *(const float4*)(row + 8 * cn + 4);

    float e0 = __expf(a0.x), e1 = __expf(a0.y), e2 = __expf(a0.z),
          e3 = __expf(a0.w), e4 = __expf(a1.x), e5 = __expf(a1.y),
          e6 = __expf(a1.z), e7 = __expf(a1.w);

#pragma unroll
    for (int k = 0; k < 8; ++k) {
      if (c == 0 && k == 0) continue;  // t=0 consumed by init

      // replicate q row-groups to all lanes: qr_g[j] = q[16g + (j&15)]
      unsigned qb = fiu(q);
      auto h = __builtin_amdgcn_permlane16_swap(qb, qb, false, false);
      auto A = __builtin_amdgcn_permlane32_swap(h[0], h[0], false, false);
      auto B = __builtin_amdgcn_permlane32_swap(h[1], h[1], false, false);
      float qr0 = uif(A[0]), qr2 = uif(A[1]);
      float qr1 = uif(B[0]), qr3 = uif(B[1]);

      // r=0 chain starts (plain muls)
      float accA0 = qr0 * Em[0][0];
      float accA1 = qr1 * Em[1][0];
      float accA2 = qr2 * Em[2][0];
      float accA3 = qr3 * Em[3][0];
      float accB0, accB1, accB2, accB3;
      asm volatile("s_nop 1" :::);  // VALU-write -> DPP-read hazard guard
      MUL_DPP(accB0, qr0, Em[0][1], 1);
      MUL_DPP(accB1, qr1, Em[1][1], 1);
      MUL_DPP(accB2, qr2, Em[2][1], 1);
      MUL_DPP(accB3, qr3, Em[3][1], 1);
      ROWPAIR(2, 3);   ROWPAIR(4, 5);   ROWPAIR(6, 7);
      ROWPAIR(8, 9);   ROWPAIR(10, 11); ROWPAIR(12, 13);
      ROWPAIR(14, 15);
      float s = ((accA0 + accB0) + (accA1 + accB1)) +
                ((accA2 + accB2) + (accA3 + accB3));
      float ee = (k == 0) ? e0 : (k == 1) ? e1 : (k == 2) ? e2 : (k == 3) ? e3
               : (k == 4) ? e4 : (k == 5) ? e5 : (k == 6) ? e6 : e7;
      q = s * ee;

      // exact power-of-two renorm every 4 steps (lane-0 exponent proxy)
      if ((k & 3) == 3) {
        int q0 = __builtin_amdgcn_readfirstlane((int)fiu(q));
        int e = ((q0 >> 23) & 0xff) - 126;
        carry += e;
        q = uif(fiu(q) - (unsigned)(e << 23));
      }
    }
    a0 = b0; a1 = b1;
  }

  // log_Z = ln2*carry + log(sum_j q[j])
  float s = q;
#pragma unroll
  for (int off = 32; off > 0; off >>= 1) s += __shfl_xor(s, off, 64);
  if (j == 0) {
    float logZ = (float)carry * 0.6931471805599453f + __logf(s);
    atomicAdd(out, logZ * (1.0f / NB));
  }
}

__device__ __forceinline__ void crf_gold_block(const float* __restrict__ obs,
                                               const float* __restrict__ trans,
                                               const int* __restrict__ tgt,
                                               float* __restrict__ out, int n) {
  const int tid = threadIdx.x;
  const int* __restrict__ trow = tgt + (size_t)n * LL;
  float acc = 0.f;
  for (int t = tid; t < LL; t += 256) {
    int s = trow[t];
    acc += obs[((size_t)n * CS + s) * (size_t)LL + t];
    if (t + 1 < LL) acc += trans[s * CS + trow[t + 1]];
  }
#pragma unroll
  for (int off = 32; off > 0; off >>= 1) acc += __shfl_xor(acc, off, 64);
  __shared__ float red[4];
  if ((tid & 63) == 0) red[tid >> 6] = acc;
  __syncthreads();
  if (tid == 0) {
    float tot = red[0] + red[1] + red[2] + red[3];
    atomicAdd(out, -tot * (1.0f / NB));
  }
}

// Fused: blocks [0,64) scan (threads 0-63 active), blocks [64,128) gold.
// amdgpu_waves_per_eu(1,1): MAX 1 wave/EU tells the allocator occupancy
// cannot exceed 1, disabling the occupancy heuristic that was spilling the
// 64 Em values at VGPR_Count~48-68 in R1-R5 (launch_bounds can only set min).
__global__ __launch_bounds__(256)
__attribute__((amdgpu_waves_per_eu(1, 1)))
void crf_fused(const float* __restrict__ obs, const float* __restrict__ trans,
               const int* __restrict__ tgt, float* __restrict__ out) {
  const int b = blockIdx.x;
  if (b < NB) {
    if (threadIdx.x < 64)
      crf_scan_block(obs, trans, out, b, threadIdx.x);
  } else {
    crf_gold_block(obs, trans, tgt, out, b - NB);
  }
}

extern "C" void kernel_launch(void* const* d_in, const int* in_sizes, int n_in,
                              void* d_out, int out_size, void* d_ws, size_t ws_size,
                              hipStream_t stream) {
  const float* obs   = (const float*)d_in[0];
  const float* trans = (const float*)d_in[1];
  const int*   tgt   = (const int*)d_in[2];
  float* out = (float*)d_out;

  hipMemsetAsync(out, 0, sizeof(float), stream);
  crf_fused<<<2 * NB, 256, 0, stream>>>(obs, trans, tgt, out);
}